// Round 14
// baseline (677.590 us; speedup 1.0000x reference)
//
#include <hip/hip_runtime.h>

#define N_NODES_C 100000
#define N_REL_C 5
#define N_TOT (N_REL_C * N_NODES_C)
#define FEAT 128
#define KTOT 768        // virtual K = 128 (root) + 5*128 (relations)
#define BM 128          // GEMM block rows
#define GBK 64          // GEMM K-tile
#define NPART 2048      // blocks for XCD-partitioned count/fill (multiple of 8)

typedef __attribute__((ext_vector_type(8))) short bf16x8;
typedef __attribute__((ext_vector_type(4))) float f32x4;

__device__ inline unsigned short f2bf(float f) {
    union { float f; unsigned int u; } v; v.f = f;
    return (unsigned short)((v.u + 0x7FFFu + ((v.u >> 16) & 1u)) >> 16);
}

// packed f32x2 -> bf16x2 (RNE) in one VALU instr
__device__ __forceinline__ unsigned int cvt_pk_bf16(float lo, float hi) {
    unsigned int r;
    asm("v_cvt_pk_bf16_f32 %0, %1, %2" : "=v"(r) : "v"(lo), "v"(hi));
    return r;
}

// async 16B global->LDS: lds dest = wave-uniform base + lane*16 (m97 pattern)
__device__ __forceinline__ void g2l16(const void* g, void* l) {
    __builtin_amdgcn_global_load_lds((const __attribute__((address_space(1))) unsigned int*)g,
                                     (__attribute__((address_space(3))) unsigned int*)l,
                                     16, 0, 0);
}

// unpack 8 bf16 (uint4) into 4 float2 accumulators via vector adds
__device__ __forceinline__ void accp(float2 (&a)[4], uint4 u) {
    union { unsigned int u; float f; } t;
    float2 v;
    t.u = u.x << 16;         v.x = t.f;
    t.u = u.x & 0xFFFF0000u; v.y = t.f;
    a[0] += v;
    t.u = u.y << 16;         v.x = t.f;
    t.u = u.y & 0xFFFF0000u; v.y = t.f;
    a[1] += v;
    t.u = u.z << 16;         v.x = t.f;
    t.u = u.z & 0xFFFF0000u; v.y = t.f;
    a[2] += v;
    t.u = u.w << 16;         v.x = t.f;
    t.u = u.w & 0xFFFF0000u; v.y = t.f;
    a[3] += v;
}

// ---------------------------------------------------------------------------
// preprocessing: key prepass -> partitioned count -> fused scan/inv -> fill
// (v12 structure: key cached once; 8-class XCD-partitioned atomics; fused
// inv into scan_block; scan_add writes cursor; convert_w single launch)
// ---------------------------------------------------------------------------
__global__ __launch_bounds__(256) void prep_key(const int* __restrict__ dst,
                                                const int* __restrict__ et,
                                                int* __restrict__ key, int E) {
    int e = blockIdx.x * 256 + threadIdx.x;
    if (e < E) key[e] = et[e] * N_NODES_C + dst[e];
}

__global__ __launch_bounds__(256) void count_part(const int* __restrict__ key,
                                                  int* __restrict__ cnt, int E) {
    int cls = blockIdx.x & 7;
    int base = (blockIdx.x >> 3) * 256 + threadIdx.x;
    int stride = (gridDim.x >> 3) << 8;
    for (int e = base; e < E; e += stride) {
        int k = key[e];
        if ((k >> 16) == cls) atomicAdd(&cnt[k], 1);
    }
}

__global__ __launch_bounds__(256) void fill_part(const int* __restrict__ src,
                                                 const int* __restrict__ key,
                                                 int* __restrict__ cursor,
                                                 int* __restrict__ esrc, int E) {
    int cls = blockIdx.x & 7;
    int base = (blockIdx.x >> 3) * 256 + threadIdx.x;
    int stride = (gridDim.x >> 3) << 8;
    for (int e = base; e < E; e += stride) {
        int k = key[e];
        if ((k >> 16) == cls) {
            int pos = atomicAdd(&cursor[k], 1);
            esrc[pos] = src[e];
        }
    }
}

// block-level exclusive scan of cnt; also emits inv = 1/max(cnt,1) (fused)
__global__ __launch_bounds__(256) void scan_block(const int* __restrict__ cnt,
                                                  int* __restrict__ rowptr,
                                                  int* __restrict__ bsum,
                                                  float* __restrict__ inv, int n) {
    __shared__ int sh[256];
    int tid = threadIdx.x;
    int i = blockIdx.x * 256 + tid;
    int v = (i < n) ? cnt[i] : 0;
    if (i < n) inv[i] = 1.0f / (float)(v > 1 ? v : 1);
    sh[tid] = v;
    __syncthreads();
#pragma unroll
    for (int o = 1; o < 256; o <<= 1) {
        int t = (tid >= o) ? sh[tid - o] : 0;
        __syncthreads();
        sh[tid] += t;
        __syncthreads();
    }
    if (i < n) rowptr[i] = sh[tid] - v;
    if (tid == 255) bsum[blockIdx.x] = sh[255];
}

__global__ __launch_bounds__(256) void scan_bsum(int* __restrict__ bsum, int nb) {
    __shared__ int sh[256];
    __shared__ int carry;
    int tid = threadIdx.x;
    if (tid == 0) carry = 0;
    __syncthreads();
    for (int base = 0; base < nb; base += 256) {
        int i = base + tid;
        int v = (i < nb) ? bsum[i] : 0;
        sh[tid] = v;
        __syncthreads();
#pragma unroll
        for (int o = 1; o < 256; o <<= 1) {
            int t = (tid >= o) ? sh[tid - o] : 0;
            __syncthreads();
            sh[tid] += t;
            __syncthreads();
        }
        int excl = sh[tid] - v + carry;
        int chunk_total = sh[255];
        __syncthreads();
        if (i < nb) bsum[i] = excl;
        if (tid == 0) carry += chunk_total;
        __syncthreads();
    }
}

// adds block offsets; writes cursor copy too (replaces hipMemcpyAsync)
__global__ __launch_bounds__(256) void scan_add(int* __restrict__ rowptr,
                                                int* __restrict__ cursor,
                                                const int* __restrict__ bsum,
                                                int n, int Etot) {
    int i = blockIdx.x * 256 + threadIdx.x;
    if (i < n) {
        int v = rowptr[i] + bsum[blockIdx.x];
        rowptr[i] = v;
        cursor[i] = v;
    }
    if (i == 0) rowptr[n] = Etot;
}

// ---------------------------------------------------------------------------
// conversions to bf16
// ---------------------------------------------------------------------------
__global__ __launch_bounds__(256) void convert_x(const float* __restrict__ x,
                                                 unsigned short* __restrict__ xb, int n4) {
    int i = blockIdx.x * 256 + threadIdx.x;
    if (i >= n4) return;
    float4 v = ((const float4*)x)[i];
    ushort4 o;
    o.x = f2bf(v.x); o.y = f2bf(v.y); o.z = f2bf(v.z); o.w = f2bf(v.w);
    ((ushort4*)xb)[i] = o;
}

// Bt[c][kv] per layer (col-major over virtual K); all 3 layers in one launch
__global__ __launch_bounds__(256) void convert_w3(const float* __restrict__ r0,
                                                  const float* __restrict__ w0,
                                                  const float* __restrict__ r1,
                                                  const float* __restrict__ w1,
                                                  const float* __restrict__ r2,
                                                  const float* __restrict__ w2,
                                                  unsigned short* __restrict__ BtAll) {
    int idx = blockIdx.x * 256 + threadIdx.x;
    if (idx >= FEAT * KTOT) return;
    int l = blockIdx.y;
    const float* root = (l == 0) ? r0 : ((l == 1) ? r1 : r2);
    const float* W    = (l == 0) ? w0 : ((l == 1) ? w1 : w2);
    int c = idx / KTOT;
    int kv = idx - c * KTOT;
    float val;
    if (kv < FEAT) {
        val = root[kv * FEAT + c];
    } else {
        int r = (kv - FEAT) >> 7;
        int kk = (kv - FEAT) & 127;
        val = W[((size_t)r * FEAT + kk) * FEAT + c];
    }
    BtAll[(size_t)l * FEAT * KTOT + idx] = f2bf(val);
}

// ---------------------------------------------------------------------------
// gather: agg[r][local][:] = mean over CSR[r][node] of hb[src][:]  (bf16 out)
// R7-verified structure (77us @ CL=100000 = fabric floor; FETCH 187MB =
// hb working set x 8 XCDs). v13: CL=50000 chunks -> agg chunk 64MB stays
// L3-resident between gather-write and gemm-read (kills the HBM round-trip).
// ---------------------------------------------------------------------------
__global__ __launch_bounds__(256) void gather_mean(const unsigned short* __restrict__ hb,
                                                   const int* __restrict__ esrc,
                                                   const int* __restrict__ rowptr,
                                                   const float* __restrict__ inv,
                                                   unsigned short* __restrict__ agg,
                                                   int chunk0, int CL) {
    int qw = threadIdx.x >> 4;       // 0..15 quarter-waves per block
    int seg = threadIdx.x & 15;      // feats [seg*8, seg*8+8)
    int local = blockIdx.x * 16 + qw;
    if (local >= CL) return;
    int r = blockIdx.y;
    int node = chunk0 + local;
    int lo = rowptr[r * N_NODES_C + node];
    int hi = rowptr[r * N_NODES_C + node + 1];

    float2 a0[4], a1[4];
#pragma unroll
    for (int j = 0; j < 4; j++) {
        a0[j] = make_float2(0.f, 0.f);
        a1[j] = make_float2(0.f, 0.f);
    }

    const unsigned short* hseg = hb + seg * 8;

    int e = lo;
    for (; e + 4 <= hi; e += 4) {
        int s0 = esrc[e];
        int s1 = esrc[e + 1];
        int s2 = esrc[e + 2];
        int s3 = esrc[e + 3];
        uint4 u0 = *(const uint4*)(hseg + ((size_t)s0 << 7));
        uint4 u1 = *(const uint4*)(hseg + ((size_t)s1 << 7));
        uint4 u2 = *(const uint4*)(hseg + ((size_t)s2 << 7));
        uint4 u3 = *(const uint4*)(hseg + ((size_t)s3 << 7));
        accp(a0, u0);
        accp(a1, u1);
        accp(a0, u2);
        accp(a1, u3);
    }
    if (e + 2 <= hi) {
        int s0 = esrc[e];
        int s1 = esrc[e + 1];
        uint4 u0 = *(const uint4*)(hseg + ((size_t)s0 << 7));
        uint4 u1 = *(const uint4*)(hseg + ((size_t)s1 << 7));
        accp(a0, u0);
        accp(a1, u1);
        e += 2;
    }
    if (e < hi) {
        int s = esrc[e];
        uint4 u = *(const uint4*)(hseg + ((size_t)s << 7));
        accp(a0, u);
    }

    float sc = inv[r * N_NODES_C + node];
    float2 s;
    uint4 o;
    s.x = a0[0].x + a1[0].x; s.y = a0[0].y + a1[0].y;
    o.x = cvt_pk_bf16(s.x * sc, s.y * sc);
    s.x = a0[1].x + a1[1].x; s.y = a0[1].y + a1[1].y;
    o.y = cvt_pk_bf16(s.x * sc, s.y * sc);
    s.x = a0[2].x + a1[2].x; s.y = a0[2].y + a1[2].y;
    o.z = cvt_pk_bf16(s.x * sc, s.y * sc);
    s.x = a0[3].x + a1[3].x; s.y = a0[3].y + a1[3].y;
    o.w = cvt_pk_bf16(s.x * sc, s.y * sc);
    *(uint4*)(agg + (((size_t)r * CL + local) << 7) + seg * 8) = o;
}

// ---------------------------------------------------------------------------
// MFMA GEMM (m97-style): C[n][0:128] = relu( A_virt[n][0:768] @ B + bias )
//   A_virt k<128 -> hb[node][k]; k>=128 -> agg[r][local][k%128] (pre-scaled means)
// BK=64, global_load_lds(16B) staging into unpadded LDS with chunk-XOR swizzle
// (c ^ (row&7)); reader applies same XOR -> 2-way bank aliasing (free, m136).
// Block 128x128, 4 waves 2x2, wave tile 64x64 (4x4 MFMA 16x16x32 tiles).
// ---------------------------------------------------------------------------
__global__ __launch_bounds__(256) void rgcn_gemm(const unsigned short* __restrict__ hb,
                                                 const unsigned short* __restrict__ agg,
                                                 const unsigned short* __restrict__ Bt,
                                                 const float* __restrict__ bias,
                                                 float* __restrict__ outf,
                                                 unsigned short* __restrict__ outb,
                                                 int chunk0, int CL) {
    __shared__ unsigned short As[BM * GBK];    // 16 KB
    __shared__ unsigned short Bs[FEAT * GBK];  // 16 KB

    const int tid = threadIdx.x;
    const int w = tid >> 6, lane = tid & 63;
    const int wr = w >> 1, wc = w & 1;
    const int lm = lane & 15, lq = lane >> 4;
    const int brow0 = blockIdx.x * BM;

    f32x4 acc[4][4];
#pragma unroll
    for (int i = 0; i < 4; i++)
#pragma unroll
        for (int j = 0; j < 4; j++) acc[i][j] = (f32x4){0.f, 0.f, 0.f, 0.f};

    // staging geometry: 1024 16B-chunks per tile; instr i of wave w covers
    // chunk ids cid = (w*4+i)*64 + lane; cid -> (row = cid>>3, c = cid&7).
    // source chunk is XOR-swizzled: cs = c ^ (row&7).
    size_t hboff[4];   // hb row offset + swizzled chunk (add kb)
    size_t aggoff[4];  // agg row offset + swizzled chunk (add rel term)
    size_t boff[4];    // Bt col offset + swizzled chunk (add kb)
    int ldsbase[4];    // wave-uniform LDS ushort base per instr
#pragma unroll
    for (int i = 0; i < 4; i++) {
        int cid = (w * 4 + i) * 64 + lane;
        int row = cid >> 3;
        int cs = (cid & 7) ^ (row & 7);
        int gr = brow0 + row;
        if (gr >= CL) gr = CL - 1;
        hboff[i]  = ((size_t)(chunk0 + gr) << 7) + cs * 8;
        aggoff[i] = ((size_t)gr << 7) + cs * 8;
        boff[i]   = (size_t)row * KTOT + cs * 8;   // row doubles as col for B
        ldsbase[i] = ((w * 4 + i) * 64) * 8;
    }

    for (int kb = 0; kb < KTOT; kb += GBK) {
        __syncthreads();   // prev-iter LDS reads done before overwrite
        if (kb < FEAT) {
#pragma unroll
            for (int i = 0; i < 4; i++)
                g2l16(hb + hboff[i] + kb, &As[ldsbase[i]]);
        } else {
            size_t reloff = (((size_t)((kb - FEAT) >> 7)) * CL << 7) + (size_t)((kb - FEAT) & 127);
#pragma unroll
            for (int i = 0; i < 4; i++)
                g2l16(agg + aggoff[i] + reloff, &As[ldsbase[i]]);
        }
#pragma unroll
        for (int i = 0; i < 4; i++)
            g2l16(Bt + boff[i] + kb, &Bs[ldsbase[i]]);
        __syncthreads();   // compiler emits vmcnt(0) drain before barrier

#pragma unroll
        for (int h = 0; h < 2; h++) {
            bf16x8 af[4], bf[4];
#pragma unroll
            for (int t = 0; t < 4; t++) {
                int row = wr * 64 + t * 16 + lm;
                int ca = (h * 4 + lq) ^ (row & 7);
                af[t] = *(const bf16x8*)&As[row * GBK + ca * 8];
                int col = wc * 64 + t * 16 + lm;
                int cb = (h * 4 + lq) ^ (col & 7);
                bf[t] = *(const bf16x8*)&Bs[col * GBK + cb * 8];
            }
#pragma unroll
            for (int i = 0; i < 4; i++)
#pragma unroll
                for (int j = 0; j < 4; j++)
                    acc[i][j] = __builtin_amdgcn_mfma_f32_16x16x32_bf16(af[i], bf[j], acc[i][j], 0, 0, 0);
        }
    }

    float bcol[4];
#pragma unroll
    for (int j = 0; j < 4; j++) bcol[j] = bias[wc * 64 + j * 16 + lm];

#pragma unroll
    for (int i = 0; i < 4; i++) {
#pragma unroll
        for (int reg = 0; reg < 4; reg++) {
            int lr = brow0 + wr * 64 + i * 16 + lq * 4 + reg;
            if (lr < CL) {
                size_t grow = (size_t)(chunk0 + lr) << 7;
#pragma unroll
                for (int j = 0; j < 4; j++) {
                    float v = acc[i][j][reg] + bcol[j];
                    v = fmaxf(v, 0.f);
                    int col = wc * 64 + j * 16 + lm;
                    if (outf) outf[grow + col] = v;
                    else outb[grow + col] = f2bf(v);
                }
            }
        }
    }
}

// ---------------------------------------------------------------------------
extern "C" void kernel_launch(void* const* d_in, const int* in_sizes, int n_in,
                              void* d_out, int out_size, void* d_ws, size_t ws_size,
                              hipStream_t stream) {
    const float* x = (const float*)d_in[0];
    const int* ei  = (const int*)d_in[1];
    const int* et  = (const int*)d_in[2];
    const int E = in_sizes[2];
    const int* src  = ei;
    const int* dstp = ei + E;

    // workspace layout:
    //   inv    @ 0           (2,000,000)
    //   rowptr @ 2,097,152   (2,000,004)
    //   esrc   @ 4,194,304   (6,400,000)
    //   xbA    @ 10,616,832  (25,600,000)
    //   xbB    @ 36,306,944  (25,600,000)
    //   agg    @ 61,997,056  (CL*1280 bytes)  [cnt/cursor/bsum/key alias here]
    //   Bt     @ 61,997,056 + CL*1280 (1,769,472 = 3 layers)
    // v13: CL=50000 (2 chunks) -- agg chunk (64MB) stays L3-resident between
    // gather-write and gemm-read, removing the agg HBM round-trip.
    int CL = 25000;
    if (ws_size >= 61997056ull + 50000ull * 1280ull + 1769472ull) CL = 50000;
    const int NCHUNK = N_NODES_C / CL;

    char* ws = (char*)d_ws;
    float* inv             = (float*)ws;
    int*   rowptr          = (int*)(ws + 2097152);
    int*   esrc            = (int*)(ws + 4194304);
    unsigned short* xbA    = (unsigned short*)(ws + 10616832);
    unsigned short* xbB    = (unsigned short*)(ws + 36306944);
    unsigned short* agg    = (unsigned short*)(ws + 61997056);
    unsigned short* BtAll  = (unsigned short*)(ws + 61997056 + (size_t)CL * 1280ull);
    int*   cnt    = (int*)(ws + 61997056);             // alias agg (dead before gathers)
    int*   cursor = (int*)(ws + 61997056 + 2097152);   // alias agg
    int*   bsum   = (int*)(ws + 61997056 + 4194304);   // alias agg
    int*   key    = (int*)(ws + 61997056 + 8388608);   // alias agg (6.4MB)

    const int nscan_blocks = (N_TOT + 255) / 256;

    hipMemsetAsync(cnt, 0, (size_t)N_TOT * 4, stream);
    prep_key<<<(E + 255) / 256, 256, 0, stream>>>(dstp, et, key, E);
    count_part<<<NPART, 256, 0, stream>>>(key, cnt, E);
    scan_block<<<nscan_blocks, 256, 0, stream>>>(cnt, rowptr, bsum, inv, N_TOT);
    scan_bsum<<<1, 256, 0, stream>>>(bsum, nscan_blocks);
    scan_add<<<nscan_blocks, 256, 0, stream>>>(rowptr, cursor, bsum, N_TOT, E);
    fill_part<<<NPART, 256, 0, stream>>>(src, key, cursor, esrc, E);

    const int n4 = N_NODES_C * FEAT / 4;
    convert_x<<<(n4 + 255) / 256, 256, 0, stream>>>(x, xbA, n4);

    const int nw = FEAT * KTOT;
    convert_w3<<<dim3((nw + 255) / 256, 3), 256, 0, stream>>>(
        (const float*)d_in[4], (const float*)d_in[3],
        (const float*)d_in[7], (const float*)d_in[6],
        (const float*)d_in[10], (const float*)d_in[9], BtAll);

    const float* Bp[3] = {(const float*)d_in[5], (const float*)d_in[8], (const float*)d_in[11]};

    const int gemm_grid = (CL + BM - 1) / BM;
    dim3 ggrid((CL + 15) / 16, N_REL_C);

    // layer dataflow (bf16 ping-pong): xbA -> xbB -> xbA -> d_out(fp32)
    for (int l = 0; l < 3; l++) {
        const unsigned short* hin = (l == 1) ? xbB : xbA;
        unsigned short* outb = (l == 0) ? xbB : ((l == 1) ? xbA : nullptr);
        float* outf = (l == 2) ? (float*)d_out : nullptr;
        for (int c = 0; c < NCHUNK; c++) {
            gather_mean<<<ggrid, 256, 0, stream>>>(hin, esrc, rowptr, inv, agg,
                                                   c * CL, CL);
            rgcn_gemm<<<gemm_grid, 256, 0, stream>>>(hin, agg, BtAll + (size_t)l * nw,
                                                     Bp[l], outf, outb, c * CL, CL);
        }
    }
}

// Round 15
// 638.360 us; speedup vs baseline: 1.0615x; 1.0615x over previous
//
#include <hip/hip_runtime.h>

#define N_NODES_C 100000
#define N_REL_C 5
#define N_TOT (N_REL_C * N_NODES_C)
#define FEAT 128
#define KTOT 768        // virtual K = 128 (root) + 5*128 (relations)
#define BM 128          // GEMM block rows
#define GBK 64          // GEMM K-tile
#define NPART 2048      // blocks for XCD-partitioned fill (multiple of 8)

typedef __attribute__((ext_vector_type(8))) short bf16x8;
typedef __attribute__((ext_vector_type(4))) float f32x4;

__device__ inline unsigned short f2bf(float f) {
    union { float f; unsigned int u; } v; v.f = f;
    return (unsigned short)((v.u + 0x7FFFu + ((v.u >> 16) & 1u)) >> 16);
}

// packed f32x2 -> bf16x2 (RNE) in one VALU instr
__device__ __forceinline__ unsigned int cvt_pk_bf16(float lo, float hi) {
    unsigned int r;
    asm("v_cvt_pk_bf16_f32 %0, %1, %2" : "=v"(r) : "v"(lo), "v"(hi));
    return r;
}

// async 16B global->LDS: lds dest = wave-uniform base + lane*16 (m97 pattern)
__device__ __forceinline__ void g2l16(const void* g, void* l) {
    __builtin_amdgcn_global_load_lds((const __attribute__((address_space(1))) unsigned int*)g,
                                     (__attribute__((address_space(3))) unsigned int*)l,
                                     16, 0, 0);
}

// unpack 8 bf16 (uint4) into 4 float2 accumulators via vector adds
__device__ __forceinline__ void accp(float2 (&a)[4], uint4 u) {
    union { unsigned int u; float f; } t;
    float2 v;
    t.u = u.x << 16;         v.x = t.f;
    t.u = u.x & 0xFFFF0000u; v.y = t.f;
    a[0] += v;
    t.u = u.y << 16;         v.x = t.f;
    t.u = u.y & 0xFFFF0000u; v.y = t.f;
    a[1] += v;
    t.u = u.z << 16;         v.x = t.f;
    t.u = u.z & 0xFFFF0000u; v.y = t.f;
    a[2] += v;
    t.u = u.w << 16;         v.x = t.f;
    t.u = u.w & 0xFFFF0000u; v.y = t.f;
    a[3] += v;
}

// ---------------------------------------------------------------------------
// preprocessing (v14): fused key+count single pass -> scan(+inv) -> fill.
// R14 counters showed device-scope atomics are effectively memory-side RMW
// (fill WRITE 78MB ~ 1.6M x 48B regardless of partitioning), so count gains
// nothing from the 8-class key re-scan (FETCH 50MB = 8 x key). Monolithic
// fused prep_count has the same atomic cost but kills one 51MB scan pass.
// fill stays partitioned: its 118->68us win was esrc STORE locality.
// ---------------------------------------------------------------------------
__global__ __launch_bounds__(256) void prep_count(const int* __restrict__ dst,
                                                  const int* __restrict__ et,
                                                  int* __restrict__ key,
                                                  int* __restrict__ cnt, int E) {
    int e = blockIdx.x * 256 + threadIdx.x;
    if (e < E) {
        int k = et[e] * N_NODES_C + dst[e];
        key[e] = k;
        atomicAdd(&cnt[k], 1);
    }
}

__global__ __launch_bounds__(256) void fill_part(const int* __restrict__ src,
                                                 const int* __restrict__ key,
                                                 int* __restrict__ cursor,
                                                 int* __restrict__ esrc, int E) {
    int cls = blockIdx.x & 7;
    int base = (blockIdx.x >> 3) * 256 + threadIdx.x;
    int stride = (gridDim.x >> 3) << 8;
    for (int e = base; e < E; e += stride) {
        int k = key[e];
        if ((k >> 16) == cls) {
            int pos = atomicAdd(&cursor[k], 1);
            esrc[pos] = src[e];
        }
    }
}

// block-level exclusive scan of cnt; also emits inv = 1/max(cnt,1) (fused)
__global__ __launch_bounds__(256) void scan_block(const int* __restrict__ cnt,
                                                  int* __restrict__ rowptr,
                                                  int* __restrict__ bsum,
                                                  float* __restrict__ inv, int n) {
    __shared__ int sh[256];
    int tid = threadIdx.x;
    int i = blockIdx.x * 256 + tid;
    int v = (i < n) ? cnt[i] : 0;
    if (i < n) inv[i] = 1.0f / (float)(v > 1 ? v : 1);
    sh[tid] = v;
    __syncthreads();
#pragma unroll
    for (int o = 1; o < 256; o <<= 1) {
        int t = (tid >= o) ? sh[tid - o] : 0;
        __syncthreads();
        sh[tid] += t;
        __syncthreads();
    }
    if (i < n) rowptr[i] = sh[tid] - v;
    if (tid == 255) bsum[blockIdx.x] = sh[255];
}

__global__ __launch_bounds__(256) void scan_bsum(int* __restrict__ bsum, int nb) {
    __shared__ int sh[256];
    __shared__ int carry;
    int tid = threadIdx.x;
    if (tid == 0) carry = 0;
    __syncthreads();
    for (int base = 0; base < nb; base += 256) {
        int i = base + tid;
        int v = (i < nb) ? bsum[i] : 0;
        sh[tid] = v;
        __syncthreads();
#pragma unroll
        for (int o = 1; o < 256; o <<= 1) {
            int t = (tid >= o) ? sh[tid - o] : 0;
            __syncthreads();
            sh[tid] += t;
            __syncthreads();
        }
        int excl = sh[tid] - v + carry;
        int chunk_total = sh[255];
        __syncthreads();
        if (i < nb) bsum[i] = excl;
        if (tid == 0) carry += chunk_total;
        __syncthreads();
    }
}

// adds block offsets; writes cursor copy too (replaces hipMemcpyAsync)
__global__ __launch_bounds__(256) void scan_add(int* __restrict__ rowptr,
                                                int* __restrict__ cursor,
                                                const int* __restrict__ bsum,
                                                int n, int Etot) {
    int i = blockIdx.x * 256 + threadIdx.x;
    if (i < n) {
        int v = rowptr[i] + bsum[blockIdx.x];
        rowptr[i] = v;
        cursor[i] = v;
    }
    if (i == 0) rowptr[n] = Etot;
}

// ---------------------------------------------------------------------------
// conversions to bf16
// ---------------------------------------------------------------------------
__global__ __launch_bounds__(256) void convert_x(const float* __restrict__ x,
                                                 unsigned short* __restrict__ xb, int n4) {
    int i = blockIdx.x * 256 + threadIdx.x;
    if (i >= n4) return;
    float4 v = ((const float4*)x)[i];
    ushort4 o;
    o.x = f2bf(v.x); o.y = f2bf(v.y); o.z = f2bf(v.z); o.w = f2bf(v.w);
    ((ushort4*)xb)[i] = o;
}

// Bt[c][kv] per layer (col-major over virtual K); all 3 layers in one launch
__global__ __launch_bounds__(256) void convert_w3(const float* __restrict__ r0,
                                                  const float* __restrict__ w0,
                                                  const float* __restrict__ r1,
                                                  const float* __restrict__ w1,
                                                  const float* __restrict__ r2,
                                                  const float* __restrict__ w2,
                                                  unsigned short* __restrict__ BtAll) {
    int idx = blockIdx.x * 256 + threadIdx.x;
    if (idx >= FEAT * KTOT) return;
    int l = blockIdx.y;
    const float* root = (l == 0) ? r0 : ((l == 1) ? r1 : r2);
    const float* W    = (l == 0) ? w0 : ((l == 1) ? w1 : w2);
    int c = idx / KTOT;
    int kv = idx - c * KTOT;
    float val;
    if (kv < FEAT) {
        val = root[kv * FEAT + c];
    } else {
        int r = (kv - FEAT) >> 7;
        int kk = (kv - FEAT) & 127;
        val = W[((size_t)r * FEAT + kk) * FEAT + c];
    }
    BtAll[(size_t)l * FEAT * KTOT + idx] = f2bf(val);
}

// ---------------------------------------------------------------------------
// gather: agg[r][local][:] = mean over CSR[r][node] of hb[src][:]  (bf16 out)
// R7/R13-verified structure (77us @ CL=100000 = fabric floor for random-row
// reads: FETCH 187MB = hb working set x 8 XCDs; insensitive to unroll depth,
// VALU count, write strategy). quarter-wave per (relation,node), x4 unroll,
// float2 accumulate, cvt_pk epilogue.
// ---------------------------------------------------------------------------
__global__ __launch_bounds__(256) void gather_mean(const unsigned short* __restrict__ hb,
                                                   const int* __restrict__ esrc,
                                                   const int* __restrict__ rowptr,
                                                   const float* __restrict__ inv,
                                                   unsigned short* __restrict__ agg,
                                                   int chunk0, int CL) {
    int qw = threadIdx.x >> 4;       // 0..15 quarter-waves per block
    int seg = threadIdx.x & 15;      // feats [seg*8, seg*8+8)
    int local = blockIdx.x * 16 + qw;
    if (local >= CL) return;
    int r = blockIdx.y;
    int node = chunk0 + local;
    int lo = rowptr[r * N_NODES_C + node];
    int hi = rowptr[r * N_NODES_C + node + 1];

    float2 a0[4], a1[4];
#pragma unroll
    for (int j = 0; j < 4; j++) {
        a0[j] = make_float2(0.f, 0.f);
        a1[j] = make_float2(0.f, 0.f);
    }

    const unsigned short* hseg = hb + seg * 8;

    int e = lo;
    for (; e + 4 <= hi; e += 4) {
        int s0 = esrc[e];
        int s1 = esrc[e + 1];
        int s2 = esrc[e + 2];
        int s3 = esrc[e + 3];
        uint4 u0 = *(const uint4*)(hseg + ((size_t)s0 << 7));
        uint4 u1 = *(const uint4*)(hseg + ((size_t)s1 << 7));
        uint4 u2 = *(const uint4*)(hseg + ((size_t)s2 << 7));
        uint4 u3 = *(const uint4*)(hseg + ((size_t)s3 << 7));
        accp(a0, u0);
        accp(a1, u1);
        accp(a0, u2);
        accp(a1, u3);
    }
    if (e + 2 <= hi) {
        int s0 = esrc[e];
        int s1 = esrc[e + 1];
        uint4 u0 = *(const uint4*)(hseg + ((size_t)s0 << 7));
        uint4 u1 = *(const uint4*)(hseg + ((size_t)s1 << 7));
        accp(a0, u0);
        accp(a1, u1);
        e += 2;
    }
    if (e < hi) {
        int s = esrc[e];
        uint4 u = *(const uint4*)(hseg + ((size_t)s << 7));
        accp(a0, u);
    }

    float sc = inv[r * N_NODES_C + node];
    float2 s;
    uint4 o;
    s.x = a0[0].x + a1[0].x; s.y = a0[0].y + a1[0].y;
    o.x = cvt_pk_bf16(s.x * sc, s.y * sc);
    s.x = a0[1].x + a1[1].x; s.y = a0[1].y + a1[1].y;
    o.y = cvt_pk_bf16(s.x * sc, s.y * sc);
    s.x = a0[2].x + a1[2].x; s.y = a0[2].y + a1[2].y;
    o.z = cvt_pk_bf16(s.x * sc, s.y * sc);
    s.x = a0[3].x + a1[3].x; s.y = a0[3].y + a1[3].y;
    o.w = cvt_pk_bf16(s.x * sc, s.y * sc);
    *(uint4*)(agg + (((size_t)r * CL + local) << 7) + seg * 8) = o;
}

// ---------------------------------------------------------------------------
// MFMA GEMM (m97-style): C[n][0:128] = relu( A_virt[n][0:768] @ B + bias )
//   A_virt k<128 -> hb[node][k]; k>=128 -> agg[r][local][k%128] (pre-scaled means)
// BK=64, global_load_lds(16B) staging into unpadded LDS with chunk-XOR swizzle
// (c ^ (row&7)); reader applies same XOR -> 2-way bank aliasing (free, m136).
// Block 128x128, 4 waves 2x2, wave tile 64x64 (4x4 MFMA 16x16x32 tiles).
// ---------------------------------------------------------------------------
__global__ __launch_bounds__(256) void rgcn_gemm(const unsigned short* __restrict__ hb,
                                                 const unsigned short* __restrict__ agg,
                                                 const unsigned short* __restrict__ Bt,
                                                 const float* __restrict__ bias,
                                                 float* __restrict__ outf,
                                                 unsigned short* __restrict__ outb,
                                                 int chunk0, int CL) {
    __shared__ unsigned short As[BM * GBK];    // 16 KB
    __shared__ unsigned short Bs[FEAT * GBK];  // 16 KB

    const int tid = threadIdx.x;
    const int w = tid >> 6, lane = tid & 63;
    const int wr = w >> 1, wc = w & 1;
    const int lm = lane & 15, lq = lane >> 4;
    const int brow0 = blockIdx.x * BM;

    f32x4 acc[4][4];
#pragma unroll
    for (int i = 0; i < 4; i++)
#pragma unroll
        for (int j = 0; j < 4; j++) acc[i][j] = (f32x4){0.f, 0.f, 0.f, 0.f};

    // staging geometry: 1024 16B-chunks per tile; instr i of wave w covers
    // chunk ids cid = (w*4+i)*64 + lane; cid -> (row = cid>>3, c = cid&7).
    // source chunk is XOR-swizzled: cs = c ^ (row&7).
    size_t hboff[4];   // hb row offset + swizzled chunk (add kb)
    size_t aggoff[4];  // agg row offset + swizzled chunk (add rel term)
    size_t boff[4];    // Bt col offset + swizzled chunk (add kb)
    int ldsbase[4];    // wave-uniform LDS ushort base per instr
#pragma unroll
    for (int i = 0; i < 4; i++) {
        int cid = (w * 4 + i) * 64 + lane;
        int row = cid >> 3;
        int cs = (cid & 7) ^ (row & 7);
        int gr = brow0 + row;
        if (gr >= CL) gr = CL - 1;
        hboff[i]  = ((size_t)(chunk0 + gr) << 7) + cs * 8;
        aggoff[i] = ((size_t)gr << 7) + cs * 8;
        boff[i]   = (size_t)row * KTOT + cs * 8;   // row doubles as col for B
        ldsbase[i] = ((w * 4 + i) * 64) * 8;
    }

    for (int kb = 0; kb < KTOT; kb += GBK) {
        __syncthreads();   // prev-iter LDS reads done before overwrite
        if (kb < FEAT) {
#pragma unroll
            for (int i = 0; i < 4; i++)
                g2l16(hb + hboff[i] + kb, &As[ldsbase[i]]);
        } else {
            size_t reloff = (((size_t)((kb - FEAT) >> 7)) * CL << 7) + (size_t)((kb - FEAT) & 127);
#pragma unroll
            for (int i = 0; i < 4; i++)
                g2l16(agg + aggoff[i] + reloff, &As[ldsbase[i]]);
        }
#pragma unroll
        for (int i = 0; i < 4; i++)
            g2l16(Bt + boff[i] + kb, &Bs[ldsbase[i]]);
        __syncthreads();   // compiler emits vmcnt(0) drain before barrier

#pragma unroll
        for (int h = 0; h < 2; h++) {
            bf16x8 af[4], bf[4];
#pragma unroll
            for (int t = 0; t < 4; t++) {
                int row = wr * 64 + t * 16 + lm;
                int ca = (h * 4 + lq) ^ (row & 7);
                af[t] = *(const bf16x8*)&As[row * GBK + ca * 8];
                int col = wc * 64 + t * 16 + lm;
                int cb = (h * 4 + lq) ^ (col & 7);
                bf[t] = *(const bf16x8*)&Bs[col * GBK + cb * 8];
            }
#pragma unroll
            for (int i = 0; i < 4; i++)
#pragma unroll
                for (int j = 0; j < 4; j++)
                    acc[i][j] = __builtin_amdgcn_mfma_f32_16x16x32_bf16(af[i], bf[j], acc[i][j], 0, 0, 0);
        }
    }

    float bcol[4];
#pragma unroll
    for (int j = 0; j < 4; j++) bcol[j] = bias[wc * 64 + j * 16 + lm];

#pragma unroll
    for (int i = 0; i < 4; i++) {
#pragma unroll
        for (int reg = 0; reg < 4; reg++) {
            int lr = brow0 + wr * 64 + i * 16 + lq * 4 + reg;
            if (lr < CL) {
                size_t grow = (size_t)(chunk0 + lr) << 7;
#pragma unroll
                for (int j = 0; j < 4; j++) {
                    float v = acc[i][j][reg] + bcol[j];
                    v = fmaxf(v, 0.f);
                    int col = wc * 64 + j * 16 + lm;
                    if (outf) outf[grow + col] = v;
                    else outb[grow + col] = f2bf(v);
                }
            }
        }
    }
}

// ---------------------------------------------------------------------------
extern "C" void kernel_launch(void* const* d_in, const int* in_sizes, int n_in,
                              void* d_out, int out_size, void* d_ws, size_t ws_size,
                              hipStream_t stream) {
    const float* x = (const float*)d_in[0];
    const int* ei  = (const int*)d_in[1];
    const int* et  = (const int*)d_in[2];
    const int E = in_sizes[2];
    const int* src  = ei;
    const int* dstp = ei + E;

    // workspace layout:
    //   inv    @ 0           (2,000,000)
    //   rowptr @ 2,097,152   (2,000,004)
    //   esrc   @ 4,194,304   (6,400,000)
    //   xbA    @ 10,616,832  (25,600,000)
    //   xbB    @ 36,306,944  (25,600,000)
    //   agg    @ 61,997,056  (CL*1280 bytes)  [cnt/cursor/bsum/key alias here]
    //   Bt     @ 61,997,056 + CL*1280 (1,769,472 = 3 layers)
    // v14: CL=100000 restored (R14 falsified the L3-residency thesis: CL=50000
    // cost +33us from hb re-fetch + GEMM underfill + extra launches).
    int CL = 25000;
    if (ws_size >= 61997056ull + 100000ull * 1280ull + 1769472ull) CL = 100000;
    else if (ws_size >= 61997056ull + 50000ull * 1280ull + 1769472ull) CL = 50000;
    const int NCHUNK = N_NODES_C / CL;

    char* ws = (char*)d_ws;
    float* inv             = (float*)ws;
    int*   rowptr          = (int*)(ws + 2097152);
    int*   esrc            = (int*)(ws + 4194304);
    unsigned short* xbA    = (unsigned short*)(ws + 10616832);
    unsigned short* xbB    = (unsigned short*)(ws + 36306944);
    unsigned short* agg    = (unsigned short*)(ws + 61997056);
    unsigned short* BtAll  = (unsigned short*)(ws + 61997056 + (size_t)CL * 1280ull);
    int*   cnt    = (int*)(ws + 61997056);             // alias agg (dead before gathers)
    int*   cursor = (int*)(ws + 61997056 + 2097152);   // alias agg
    int*   bsum   = (int*)(ws + 61997056 + 4194304);   // alias agg
    int*   key    = (int*)(ws + 61997056 + 8388608);   // alias agg (6.4MB)

    const int nscan_blocks = (N_TOT + 255) / 256;

    hipMemsetAsync(cnt, 0, (size_t)N_TOT * 4, stream);
    prep_count<<<(E + 255) / 256, 256, 0, stream>>>(dstp, et, key, cnt, E);
    scan_block<<<nscan_blocks, 256, 0, stream>>>(cnt, rowptr, bsum, inv, N_TOT);
    scan_bsum<<<1, 256, 0, stream>>>(bsum, nscan_blocks);
    scan_add<<<nscan_blocks, 256, 0, stream>>>(rowptr, cursor, bsum, N_TOT, E);
    fill_part<<<NPART, 256, 0, stream>>>(src, key, cursor, esrc, E);

    const int n4 = N_NODES_C * FEAT / 4;
    convert_x<<<(n4 + 255) / 256, 256, 0, stream>>>(x, xbA, n4);

    const int nw = FEAT * KTOT;
    convert_w3<<<dim3((nw + 255) / 256, 3), 256, 0, stream>>>(
        (const float*)d_in[4], (const float*)d_in[3],
        (const float*)d_in[7], (const float*)d_in[6],
        (const float*)d_in[10], (const float*)d_in[9], BtAll);

    const float* Bp[3] = {(const float*)d_in[5], (const float*)d_in[8], (const float*)d_in[11]};

    const int gemm_grid = (CL + BM - 1) / BM;
    dim3 ggrid((CL + 15) / 16, N_REL_C);

    // layer dataflow (bf16 ping-pong): xbA -> xbB -> xbA -> d_out(fp32)
    for (int l = 0; l < 3; l++) {
        const unsigned short* hin = (l == 1) ? xbB : xbA;
        unsigned short* outb = (l == 0) ? xbB : ((l == 1) ? xbA : nullptr);
        float* outf = (l == 2) ? (float*)d_out : nullptr;
        for (int c = 0; c < NCHUNK; c++) {
            gather_mean<<<ggrid, 256, 0, stream>>>(hin, esrc, rowptr, inv, agg,
                                                   c * CL, CL);
            rgcn_gemm<<<gemm_grid, 256, 0, stream>>>(hin, agg, BtAll + (size_t)l * nw,
                                                     Bp[l], outf, outb, c * CL, CL);
        }
    }
}